// Round 5
// baseline (320.976 us; speedup 1.0000x reference)
//
#include <hip/hip_runtime.h>
#include <hip/hip_bf16.h>

typedef __bf16 bf16x8 __attribute__((ext_vector_type(8)));
typedef float  f32x4  __attribute__((ext_vector_type(4)));

__device__ __forceinline__ ushort f2b(float f){
  union { float f; uint i; } v; v.f = f; uint u = v.i;
  return (ushort)((u + 0x7FFFu + ((u >> 16) & 1u)) >> 16);
}
__device__ __forceinline__ uint pack2(float a, float b){
  __hip_bfloat162 h = __float22bfloat162_rn(make_float2(a, b));
  union { __hip_bfloat162 h; uint u; } v; v.h = h; return v.u;
}
__device__ __forceinline__ bf16x8 ldfrag(const ushort* p){
  return *reinterpret_cast<const bf16x8*>(p);
}
__device__ __forceinline__ f32x4 relu4(f32x4 x){
  f32x4 r;
  r[0]=fmaxf(x[0],0.f); r[1]=fmaxf(x[1],0.f);
  r[2]=fmaxf(x[2],0.f); r[3]=fmaxf(x[3],0.f);
  return r;
}

// Pre-kernel: fp32 weights -> transposed bf16 layouts in workspace.
// W1ftr[n][k] (96x128) = bf16(fc1_W[3+k][n]);  W2tr[n][k] (64x96) = bf16(fc2_W[k][n]);
// decWtr[n][k] (32x32, zero-padded n>=24) = bf16(dec_W[k][n]).
__global__ void omd_transpose(const float* __restrict__ fc1W, const float* __restrict__ fc2W,
                              const float* __restrict__ decW,
                              ushort* __restrict__ W1ftr, ushort* __restrict__ W2tr,
                              ushort* __restrict__ decWtr){
  int t = blockIdx.x * 256 + threadIdx.x;
  if (t < 96*128){
    int n = t >> 7, k = t & 127;
    W1ftr[t] = f2b(fc1W[(3 + k)*96 + n]);
  } else if (t < 96*128 + 64*96){
    int e = t - 96*128;
    int n = e / 96, k = e - n*96;
    W2tr[e] = f2b(fc2W[k*64 + n]);
  } else if (t < 96*128 + 64*96 + 32*32){
    int e = t - (96*128 + 64*96);
    int n = e >> 5, k = e & 31;
    decWtr[e] = (n < 24) ? f2b(decW[k*24 + n]) : (ushort)0;
  }
}

__global__ __launch_bounds__(256, 3) void omd_main(
    const float* __restrict__ points, const float* __restrict__ feats,
    const int*   __restrict__ batch,  const float* __restrict__ decb,
    const float* __restrict__ fc1W,   const float* __restrict__ fc1b,
    const float* __restrict__ fc2b,   const ushort* __restrict__ W1ftr,
    const ushort* __restrict__ W2tr,  const ushort* __restrict__ decWtr,
    float* __restrict__ out, int npts)
{
  __shared__ __align__(16) ushort pfB[32*40];      // point_features bf16, stride 40
  __shared__ float decbL[24];
  __shared__ __align__(16) float w1pL[3*96];       // fc1_W rows 0..2 (fp32)
  __shared__ __align__(16) float relL[32*24];      // rel, fp32
  __shared__ __align__(16) ushort ffL[32*136];     // feature_features bf16, stride 136
  __shared__ __align__(16) float  s1L[32*100];     // s1 = ff@W1f+b1, pad 96->100

  const int t    = threadIdx.x;
  const int w    = t >> 6;
  const int lane = t & 63;
  const int q    = lane >> 4;
  const int c    = lane & 15;
  const int pbase = blockIdx.x * 32;

  const size_t offF = (size_t)npts * 24;                      // fc2 output offset
  const size_t offB = (size_t)npts * 24 + (size_t)npts * 512; // batch output offset

  // ---- stage LDS ----
  {
    // point features: 32 rows x 32 floats -> bf16 (stride 40)
    int p = t >> 3, seg = t & 7;
    const f32x4* src = (const f32x4*)(feats + (size_t)(pbase + p)*160);
    f32x4 f = src[seg];
    uint* dst = (uint*)pfB;
    dst[p*20 + seg*2    ] = pack2(f[0], f[1]);
    dst[p*20 + seg*2 + 1] = pack2(f[2], f[3]);
  }
  {
    // feature features: 32 rows x 128 floats -> bf16 LDS (stride 136)
    int m = t >> 3, seg = t & 7;
    const f32x4* src = (const f32x4*)(feats + (size_t)(pbase + m)*160 + 32 + seg*16);
    uint* dst = (uint*)(ffL + m*136 + seg*16);
    #pragma unroll
    for (int r = 0; r < 4; ++r){
      f32x4 f = src[r];
      dst[r*2    ] = pack2(f[0], f[1]);
      dst[r*2 + 1] = pack2(f[2], f[3]);
    }
  }
  if (t < 24) decbL[t] = decb[t];
  for (int e = t; e < 288; e += 256) w1pL[e] = fc1W[e];

  // ---- W2 B-fragments resident in registers ----
  bf16x8 w2f[4][3];
  #pragma unroll
  for (int nt = 0; nt < 4; ++nt)
    #pragma unroll
    for (int kt = 0; kt < 3; ++kt)
      w2f[nt][kt] = ldfrag(W2tr + (nt*16 + c)*96 + kt*32 + q*8);

  __syncthreads();

  // ---- phase 1: rel = pf @ dec_W + dec_b  (one MFMA per wave) ----
  {
    int mt = w & 1, ntile = w >> 1;           // ntile=1 covers cols 16..23 (c<8)
    bf16x8 a = ldfrag(pfB + (mt*16 + c)*40 + q*8);
    bf16x8 b = ldfrag(decWtr + ((ntile*16 + c)<<5) + q*8);
    f32x4 acc = {0.f, 0.f, 0.f, 0.f};
    acc = __builtin_amdgcn_mfma_f32_16x16x32_bf16(a, b, acc, 0, 0, 0);
    int n = ntile*16 + c;
    if (n < 24){
      float bb = decbL[n];
      #pragma unroll
      for (int r = 0; r < 4; ++r)
        relL[(mt*16 + q*4 + r)*24 + n] = acc[r] + bb;
    }
  }

  // ---- phase 2: s1 = ff @ W1f + b1  (MFMA 16x16x32, A from LDS) ----
  {
    int mt = w & 1, trio = w >> 1;
    const ushort* arow = ffL + (mt*16 + c)*136 + q*8;
    bf16x8 a0 = ldfrag(arow);
    bf16x8 a1 = ldfrag(arow + 32);
    bf16x8 a2 = ldfrag(arow + 64);
    bf16x8 a3 = ldfrag(arow + 96);
    #pragma unroll
    for (int i = 0; i < 3; ++i){
      const ushort* brow = W1ftr + ((trio*3 + i)*16 + c)*128 + q*8;
      f32x4 acc = {0.f, 0.f, 0.f, 0.f};
      acc = __builtin_amdgcn_mfma_f32_16x16x32_bf16(a0, ldfrag(brow      ), acc, 0, 0, 0);
      acc = __builtin_amdgcn_mfma_f32_16x16x32_bf16(a1, ldfrag(brow + 32 ), acc, 0, 0, 0);
      acc = __builtin_amdgcn_mfma_f32_16x16x32_bf16(a2, ldfrag(brow + 64 ), acc, 0, 0, 0);
      acc = __builtin_amdgcn_mfma_f32_16x16x32_bf16(a3, ldfrag(brow + 96 ), acc, 0, 0, 0);
      int col = (trio*3 + i)*16 + c;
      float bb = fc1b[col];
      #pragma unroll
      for (int r = 0; r < 4; ++r)
        s1L[(mt*16 + q*4 + r)*100 + col] = acc[r] + bb;
    }
  }
  __syncthreads();

  // ---- fc2, barrier-free: wave -> (mt = w&1, neighbor group g = w>>1) ----
  // Lane (c,q) builds h directly in MFMA A-operand layout (row c, cols kt*32+q*8..+7).
  {
    const int mt = w & 1, g = w >> 1;
    const int row = mt*16 + c;

    // rel for this row, 4 neighbors (12 contiguous floats, 16B-aligned)
    f32x4 ra = *(const f32x4*)&relL[row*24 + g*12];
    f32x4 rb = *(const f32x4*)&relL[row*24 + g*12 + 4];
    f32x4 rc = *(const f32x4*)&relL[row*24 + g*12 + 8];
    float rl[4][3] = {{ra[0],ra[1],ra[2]},{ra[3],rb[0],rb[1]},
                      {rb[2],rb[3],rc[0]},{rc[1],rc[2],rc[3]}};

    f32x4 acc[4][4];
    #pragma unroll
    for (int nt = 0; nt < 4; ++nt){
      float bb = fc2b[nt*16 + c];
      #pragma unroll
      for (int n = 0; n < 4; ++n) acc[n][nt] = (f32x4){bb, bb, bb, bb};
    }

    #pragma unroll
    for (int kt = 0; kt < 3; ++kt){
      const f32x4* s1v = (const f32x4*)&s1L[row*100 + kt*32 + q*8];
      f32x4 sA = s1v[0], sB = s1v[1];
      f32x4 wA0 = *(const f32x4*)&w1pL[      kt*32 + q*8];
      f32x4 wB0 = *(const f32x4*)&w1pL[      kt*32 + q*8 + 4];
      f32x4 wA1 = *(const f32x4*)&w1pL[ 96 + kt*32 + q*8];
      f32x4 wB1 = *(const f32x4*)&w1pL[ 96 + kt*32 + q*8 + 4];
      f32x4 wA2 = *(const f32x4*)&w1pL[192 + kt*32 + q*8];
      f32x4 wB2 = *(const f32x4*)&w1pL[192 + kt*32 + q*8 + 4];
      #pragma unroll
      for (int n = 0; n < 4; ++n){
        f32x4 hA = relu4(sA + rl[n][0]*wA0 + rl[n][1]*wA1 + rl[n][2]*wA2);
        f32x4 hB = relu4(sB + rl[n][0]*wB0 + rl[n][1]*wB1 + rl[n][2]*wB2);
        union { uint u[4]; bf16x8 v; } af;
        af.u[0] = pack2(hA[0], hA[1]);
        af.u[1] = pack2(hA[2], hA[3]);
        af.u[2] = pack2(hB[0], hB[1]);
        af.u[3] = pack2(hB[2], hB[3]);
        #pragma unroll
        for (int nt = 0; nt < 4; ++nt)
          acc[n][nt] = __builtin_amdgcn_mfma_f32_16x16x32_bf16(af.v, w2f[nt][kt], acc[n][nt], 0, 0, 0);
      }
    }

    // stores: C-layout rows = mt*16 + q*4 + r, cols = nt*16 + c
    #pragma unroll
    for (int n = 0; n < 4; ++n){
      int nn = g*4 + n;
      #pragma unroll
      for (int nt = 0; nt < 4; ++nt){
        #pragma unroll
        for (int r = 0; r < 4; ++r){
          size_t gg = (size_t)(pbase + mt*16 + q*4 + r)*8 + nn;
          out[offF + gg*64 + nt*16 + c] = fmaxf(acc[n][nt][r], 0.f);
        }
      }
    }
  }

  // ---- phase 4: output_points and output_batch (relL read-only since barrier 2) ----
  #pragma unroll
  for (int i = 0; i < 3; ++i){
    int e = t + 256*i;
    int p = e / 24, rem = e - p*24;
    int d = rem % 3;
    float v = points[(size_t)(pbase + p)*3 + d] + 0.5f * relL[e];
    out[(size_t)(pbase + p)*24 + rem] = v;
  }
  {
    int p = t >> 3, n = t & 7;
    out[offB + (size_t)(pbase + p)*8 + n] = (float)batch[pbase + p];
  }
}

extern "C" void kernel_launch(void* const* d_in, const int* in_sizes, int n_in,
                              void* d_out, int out_size, void* d_ws, size_t ws_size,
                              hipStream_t stream){
  const float* points = (const float*)d_in[0];
  const float* feats  = (const float*)d_in[1];
  const int*   batch  = (const int*)d_in[2];
  const float* decW   = (const float*)d_in[3];
  const float* decb   = (const float*)d_in[4];
  const float* fc1W   = (const float*)d_in[5];
  const float* fc1b   = (const float*)d_in[6];
  const float* fc2W   = (const float*)d_in[7];
  const float* fc2b   = (const float*)d_in[8];
  float*  outp   = (float*)d_out;
  ushort* W1ftr  = (ushort*)d_ws;
  ushort* W2tr   = W1ftr + 96*128;
  ushort* decWtr = W2tr + 64*96;

  int npts = in_sizes[2];           // 100000, divisible by 32

  omd_transpose<<<76, 256, 0, stream>>>(fc1W, fc2W, decW, W1ftr, W2tr, decWtr);
  omd_main<<<npts/32, 256, 0, stream>>>(points, feats, batch, decb,
                                        fc1W, fc1b, fc2b, W1ftr, W2tr, decWtr,
                                        outp, npts);
}